// Round 6
// baseline (515.830 us; speedup 1.0000x reference)
//
#include <hip/hip_runtime.h>
#include <math.h>

// MLA + ALiBi causal attention. fp32 in/out, bf16 MFMA internal compute.
// R6: fix R5's masking hole — a non-last chunk can contain diagonal tile
// nkv-2 (span % 8 == 1, i.e. h=12 qt>=12); mask any tile >= nkv-2 via
// mstart = clamp(nkv-2, cs, cend). Everything else identical to R5.

typedef __bf16 bf16;
typedef __bf16 bf16x8 __attribute__((ext_vector_type(8)));
typedef __bf16 bf16x4 __attribute__((ext_vector_type(4)));
typedef float f32x4 __attribute__((ext_vector_type(4)));

#define AS1 __attribute__((address_space(1)))
#define AS3 __attribute__((address_space(3)))

// Exact static work decomposition (L=2048, 128-row q tiles, 64-key kv tiles,
// chunk = 8 kv tiles, ALiBi window WH[h]): 344 direct + 448 partial chunks
// = 792 attn blocks; 168 multi-chunk groups; 448 partial buffers.
#define ATTN_BLOCKS 792
#define COMB_BLOCKS 168

__device__ __forceinline__ void g2l16(const void* g, void* l) {
  // async global->LDS, 16B per lane; LDS dest is wave-uniform base + lane*16
  __builtin_amdgcn_global_load_lds((const AS1 void*)g, (AS3 void*)l, 16, 0, 0);
}

// ---------------------------------------------------------------------------
// fp32 -> bf16 elementwise convert (n4 = element count / 4)
// ---------------------------------------------------------------------------
__device__ __forceinline__ void cvt_seg(const float* __restrict__ in,
                                        bf16* __restrict__ out, int n4) {
  int i = blockIdx.x * 256 + threadIdx.x;
  const int stride = gridDim.x * 256;
  for (; i < n4; i += stride) {
    float4 v = ((const float4*)in)[i];
    bf16x4 o;
    o[0] = (bf16)v.x; o[1] = (bf16)v.y; o[2] = (bf16)v.z; o[3] = (bf16)v.w;
    ((bf16x4*)out)[i] = o;
  }
}

__global__ __launch_bounds__(256) void cvt_f32_bf16(
    const float* __restrict__ in, bf16* __restrict__ out, int n4) {
  cvt_seg(in, out, n4);
}

__global__ __launch_bounds__(256) void cvt3_f32_bf16(
    const float* __restrict__ s0, bf16* __restrict__ d0, int n0,
    const float* __restrict__ s1, bf16* __restrict__ d1, int n1,
    const float* __restrict__ s2, bf16* __restrict__ d2, int n2) {
  cvt_seg(s0, d0, n0);
  cvt_seg(s1, d1, n1);
  cvt_seg(s2, d2, n2);
}

// ---------------------------------------------------------------------------
// fused convert+transpose: fp32 [Z][R][D] -> bf16 [Z][D][R]. R%64==0, D%64==0.
// ---------------------------------------------------------------------------
__global__ __launch_bounds__(256) void transpose_cvt(
    const float* __restrict__ in, bf16* __restrict__ out, int R, int D)
{
  __shared__ bf16 tile[64][72];
  const long long base = (long long)blockIdx.z * R * D;
  const int r0 = blockIdx.y * 64, c0 = blockIdx.x * 64;
  const int t = threadIdx.x;
#pragma unroll
  for (int i = 0; i < 4; ++i) {
    int c = i * 256 + t;
    int rr = c >> 4, cc = (c & 15) << 2;
    float4 v = *(const float4*)&in[base + (long long)(r0 + rr) * D + c0 + cc];
    tile[rr][cc + 0] = (bf16)v.x;
    tile[rr][cc + 1] = (bf16)v.y;
    tile[rr][cc + 2] = (bf16)v.z;
    tile[rr][cc + 3] = (bf16)v.w;
  }
  __syncthreads();
#pragma unroll
  for (int i = 0; i < 2; ++i) {
    int c = i * 256 + t;
    int rr = c >> 3, cc = (c & 7) << 3;
    bf16x8 v;
#pragma unroll
    for (int j = 0; j < 8; ++j) v[j] = tile[cc + j][rr];
    *(bf16x8*)&out[base + (long long)(c0 + rr) * R + r0 + cc] = v;
  }
}

// ---------------------------------------------------------------------------
// NT GEMM: C[m,n] = sum_k A[m,k]*B[n,k]. 128x128 tile, BK=32, 4 waves.
// ---------------------------------------------------------------------------
template <typename CT>
__global__ __launch_bounds__(256) void gemm_nt(
    const bf16* __restrict__ A, const bf16* __restrict__ B, CT* __restrict__ C,
    int lda, int ldb, int ldc, int K, long long sA, long long sB, long long sC)
{
  A += (long long)blockIdx.z * sA;
  B += (long long)blockIdx.z * sB;
  C += (long long)blockIdx.z * sC;

  __shared__ bf16 As[128][32];
  __shared__ bf16 Bs[128][32];

  const int t = threadIdx.x;
  const int lane = t & 63, wave = t >> 6;
  const int wm = (wave >> 1) * 64, wn = (wave & 1) * 64;
  const int m0 = blockIdx.y * 128, n0 = blockIdx.x * 128;
  const int r16 = lane & 15, q8 = (lane >> 4) * 8;

  f32x4 acc[4][4] = {};

  for (int k0 = 0; k0 < K; k0 += 32) {
    __syncthreads();
#pragma unroll
    for (int r = 0; r < 2; ++r) {
      int c = r * 256 + t;
      int row = c >> 2, col = (c & 3) << 3;
      g2l16(A + (long long)(m0 + row) * lda + (k0 + col), &As[row][col]);
      g2l16(B + (long long)(n0 + row) * ldb + (k0 + col), &Bs[row][col]);
    }
    __syncthreads();

    bf16x8 af[4], bfr[4];
#pragma unroll
    for (int i = 0; i < 4; ++i) af[i]  = *(const bf16x8*)&As[wm + i * 16 + r16][q8];
#pragma unroll
    for (int i = 0; i < 4; ++i) bfr[i] = *(const bf16x8*)&Bs[wn + i * 16 + r16][q8];
#pragma unroll
    for (int mi = 0; mi < 4; ++mi)
#pragma unroll
      for (int ni = 0; ni < 4; ++ni)
        acc[mi][ni] = __builtin_amdgcn_mfma_f32_16x16x32_bf16(af[mi], bfr[ni], acc[mi][ni], 0, 0, 0);
  }

  const int quad = lane >> 4;
#pragma unroll
  for (int mi = 0; mi < 4; ++mi)
#pragma unroll
    for (int ni = 0; ni < 4; ++ni)
#pragma unroll
      for (int r = 0; r < 4; ++r) {
        int mm = m0 + wm + mi * 16 + quad * 4 + r;
        int nn = n0 + wn + ni * 16 + r16;
        C[(long long)mm * ldc + nn] = (CT)acc[mi][ni][r];
      }
}

// ---------------------------------------------------------------------------
// Setup: build the attention chunk table. Integer-exact windows.
// WH[h] = floor(2^(4+0.5(h+1))). Entry: {meta, partIdx(-1=direct)}.
// meta = b | h<<1 | qt<<5 | cstart<<9 | clen<<16.
// Group: {meta, firstPart, nChunks, 0}. Emitted qt-descending (big first).
// ---------------------------------------------------------------------------
__global__ void attn_setup(int* __restrict__ tbl, int* __restrict__ grp) {
  if (threadIdx.x != 0 || blockIdx.x != 0) return;
  const int WH[16] = {22,32,45,64,90,128,181,256,362,512,724,1024,1448,2048,2896,4096};
  int nc = 0, np = 0, ng = 0;
  for (int qt = 15; qt >= 0; --qt)
    for (int h = 15; h >= 0; --h)
      for (int b = 0; b < 2; ++b) {
        int q0 = qt * 128, nkv = 2 * qt + 2;
        int dlo = q0 - WH[h];
        int kv_lo = dlo > 0 ? (dlo >> 6) : 0;
        int span = nkv - kv_lo;
        int nch = (span + 7) >> 3;
        int base = b | (h << 1) | (qt << 5);
        if (nch == 1) {
          tbl[2 * nc] = base | (kv_lo << 9) | (span << 16);
          tbl[2 * nc + 1] = -1;
          ++nc;
        } else {
          grp[4 * ng] = base; grp[4 * ng + 1] = np; grp[4 * ng + 2] = nch; grp[4 * ng + 3] = 0;
          ++ng;
          for (int c = 0; c < nch; ++c) {
            int cs = kv_lo + c * 8;
            int cl = nkv - cs; if (cl > 8) cl = 8;
            tbl[2 * nc] = base | (cs << 9) | (cl << 16);
            tbl[2 * nc + 1] = np;
            ++nc; ++np;
          }
        }
      }
}

// ---------------------------------------------------------------------------
// Flash attention, chunked. Block = table entry: 128 q rows of (b,h,qt) over
// KV tiles [cstart, cstart+clen). Direct entries normalize+store O; partial
// entries store unnormalized bf16 O~ + fp32 m,l for the combine kernel.
// Causal mask applied to any tile >= nkv-2 (regardless of chunk position).
// LDS XOR-swizzled at 16B chunks (conflict-free).
// ---------------------------------------------------------------------------
__global__ __launch_bounds__(256) void attn_kernel(
    const bf16* __restrict__ Q, const bf16* __restrict__ Kh,
    const bf16* __restrict__ VT, bf16* __restrict__ O,
    const int* __restrict__ tbl, float* __restrict__ ml, bf16* __restrict__ parts)
{
  const int L = 2048, HD = 128, D = 2048;
  const int meta = tbl[2 * blockIdx.x];
  const int part = tbl[2 * blockIdx.x + 1];
  const int b = meta & 1, h = (meta >> 1) & 15, qt = (meta >> 5) & 15;
  const int cs = (meta >> 9) & 127, cl = (meta >> 16) & 15;
  const int q0 = qt * 128, nkv = 2 * qt + 2;
  const int cend = cs + cl;
  // mask any diagonal tile (>= nkv-2) present in this chunk:
  const int mraw = nkv - 2 > cs ? nkv - 2 : cs;
  const int mstart = mraw < cend ? mraw : cend;

  const int t = threadIdx.x, wave = t >> 6, lane = t & 63;
  const int col = lane & 15, quad = lane >> 4;
  const float slope = exp2f(-0.5f * (float)(h + 1));
  const float slope16 = slope * 16.0f;
  const float scale = 0.08838834764831845f;   // 1/sqrt(128)

  __shared__ bf16 Ksf[64 * 128];   // [key][d],  16 chunks/row, swz mask 15
  __shared__ bf16 Vsf[128 * 64];   // [d][key],   8 chunks/row, swz mask 7
  __shared__ bf16 Psf[128 * 64];   // [q][key],   8 chunks/row, swz mask 7

  const long long qrow0 = (long long)(b * L + q0 + wave * 32);

  bf16x8 qf[2][4];
#pragma unroll
  for (int mi = 0; mi < 2; ++mi)
#pragma unroll
    for (int ks = 0; ks < 4; ++ks)
      qf[mi][ks] = *(const bf16x8*)&Q[(qrow0 + mi * 16 + col) * D + h * HD + ks * 32 + quad * 8];

  f32x4 o_acc[2][8] = {};
  float m_i[2][4], l_i[2][4];   // l lane-partial (this lane's 4 cols)
#pragma unroll
  for (int mi = 0; mi < 2; ++mi)
#pragma unroll
    for (int r = 0; r < 4; ++r) { m_i[mi][r] = -1e30f; l_i[mi][r] = 0.f; }

  const long long kbase = (long long)(h * 4096 + b * L) * HD;
  const long long vbase = (long long)(h * HD) * 4096 + b * L;

#define TILE_BODY(MASKED)                                                          \
  {                                                                                \
    const int kv0 = it << 6;                                                       \
    __syncthreads();                                                               \
    _Pragma("unroll")                                                              \
    for (int i = 0; i < 4; ++i) {                                                  \
      int P = i * 256 + t;                                                         \
      {                                                                            \
        int rr = P >> 4, cc = ((P & 15) ^ (rr & 15)) << 3;                         \
        g2l16(Kh + kbase + (long long)(kv0 + rr) * HD + cc, &Ksf[P * 8]);          \
      }                                                                            \
      {                                                                            \
        int rr = P >> 3, cc = ((P & 7) ^ (rr & 7)) << 3;                           \
        g2l16(VT + vbase + (long long)rr * 4096 + kv0 + cc, &Vsf[P * 8]);          \
      }                                                                            \
    }                                                                              \
    __syncthreads();                                                               \
    f32x4 s_acc[2][4] = {};                                                        \
    _Pragma("unroll")                                                              \
    for (int ks = 0; ks < 4; ++ks) {                                               \
      bf16x8 kf[4];                                                                \
      _Pragma("unroll")                                                            \
      for (int ni = 0; ni < 4; ++ni)                                               \
        kf[ni] = *(const bf16x8*)&Ksf[(ni * 16 + col) * 128 +                      \
                                      (((ks * 4 + quad) ^ col) << 3)];             \
      _Pragma("unroll")                                                            \
      for (int mi = 0; mi < 2; ++mi)                                               \
        _Pragma("unroll")                                                          \
        for (int ni = 0; ni < 4; ++ni)                                             \
          s_acc[mi][ni] = __builtin_amdgcn_mfma_f32_16x16x32_bf16(                 \
              qf[mi][ks], kf[ni], s_acc[mi][ni], 0, 0, 0);                         \
    }                                                                              \
    _Pragma("unroll")                                                              \
    for (int mi = 0; mi < 2; ++mi) {                                               \
      _Pragma("unroll")                                                            \
      for (int r = 0; r < 4; ++r) {                                                \
        const int rowq = wave * 32 + mi * 16 + quad * 4 + r;                       \
        const int qg = q0 + rowq;                                                  \
        const float sb = slope * (float)(qg - kv0 - col);                          \
        float sv[4];                                                               \
        _Pragma("unroll")                                                          \
        for (int ni = 0; ni < 4; ++ni) {                                           \
          float x = fmaf(s_acc[mi][ni][r], scale, (float)ni * slope16 - sb);       \
          sv[ni] = (MASKED && (kv0 + ni * 16 + col > qg)) ? -1e30f : x;            \
        }                                                                          \
        float rm = fmaxf(fmaxf(sv[0], sv[1]), fmaxf(sv[2], sv[3]));                \
        _Pragma("unroll")                                                          \
        for (int off = 1; off < 16; off <<= 1)                                     \
          rm = fmaxf(rm, __shfl_xor(rm, off, 64));                                 \
        const float mold = m_i[mi][r];                                             \
        float mnew = fmaxf(mold, rm);                                              \
        if (MASKED) mnew = fmaxf(mnew, -1e20f);                                    \
        const float alpha = __expf(mold - mnew);                                   \
        float ps = 0.f;                                                            \
        _Pragma("unroll")                                                          \
        for (int ni = 0; ni < 4; ++ni) {                                           \
          float pv = __expf(sv[ni] - mnew);                                        \
          ps += pv;                                                                \
          Psf[rowq * 64 + ((((ni * 2) + (col >> 3)) ^ (rowq & 7)) << 3) +          \
              (col & 7)] = (bf16)pv;                                               \
        }                                                                          \
        l_i[mi][r] = fmaf(alpha, l_i[mi][r], ps);                                  \
        m_i[mi][r] = mnew;                                                         \
        _Pragma("unroll")                                                          \
        for (int di = 0; di < 8; ++di) o_acc[mi][di][r] *= alpha;                  \
      }                                                                            \
    }                                                                              \
    __syncthreads();                                                               \
    _Pragma("unroll")                                                              \
    for (int kstep = 0; kstep < 2; ++kstep) {                                      \
      bf16x8 pf[2];                                                                \
      _Pragma("unroll")                                                            \
      for (int mi = 0; mi < 2; ++mi)                                               \
        pf[mi] = *(const bf16x8*)&Psf[(wave * 32 + mi * 16 + col) * 64 +           \
                                      (((kstep * 4 + quad) ^ (col & 7)) << 3)];    \
      _Pragma("unroll")                                                            \
      for (int di = 0; di < 8; ++di) {                                             \
        bf16x8 vf = *(const bf16x8*)&Vsf[(di * 16 + col) * 64 +                    \
                                         (((kstep * 4 + quad) ^ (col & 7)) << 3)]; \
        _Pragma("unroll")                                                          \
        for (int mi = 0; mi < 2; ++mi)                                             \
          o_acc[mi][di] = __builtin_amdgcn_mfma_f32_16x16x32_bf16(                 \
              pf[mi], vf, o_acc[mi][di], 0, 0, 0);                                 \
      }                                                                            \
    }                                                                              \
  }

  for (int it = cs; it < mstart; ++it) TILE_BODY(false)
  for (int it = mstart; it < cend; ++it) TILE_BODY(true)
#undef TILE_BODY

  if (part < 0) {
    // direct: normalize (reduce lane-partial l over the 16-lane row group)
#pragma unroll
    for (int mi = 0; mi < 2; ++mi)
#pragma unroll
      for (int r = 0; r < 4; ++r) {
        float lt = l_i[mi][r];
#pragma unroll
        for (int off = 1; off < 16; off <<= 1)
          lt += __shfl_xor(lt, off, 64);
        float rl = 1.0f / lt;
        long long qg = qrow0 + mi * 16 + quad * 4 + r;
#pragma unroll
        for (int di = 0; di < 8; ++di)
          O[qg * D + h * HD + di * 16 + col] = (bf16)(o_acc[mi][di][r] * rl);
      }
  } else {
    // partial: store unnormalized O~ (bf16) + m,l (fp32 per row)
    bf16* pb = parts + (long long)part * 16384;
    float* mlp = ml + (long long)part * 256;
#pragma unroll
    for (int mi = 0; mi < 2; ++mi)
#pragma unroll
      for (int r = 0; r < 4; ++r) {
        float lt = l_i[mi][r];
#pragma unroll
        for (int off = 1; off < 16; off <<= 1)
          lt += __shfl_xor(lt, off, 64);
        int rowq = wave * 32 + mi * 16 + quad * 4 + r;
        if (col == 0) { mlp[rowq] = m_i[mi][r]; mlp[128 + rowq] = lt; }
#pragma unroll
        for (int di = 0; di < 8; ++di)
          pb[rowq * 128 + di * 16 + col] = (bf16)o_acc[mi][di][r];
      }
  }
}

// ---------------------------------------------------------------------------
// Combine partial chunks: O = sum_c e^(m_c-M) O~_c / sum_c e^(m_c-M) l_c.
// One block per group; thread t: row = t>>1, cols (t&1)*64..+63.
// ---------------------------------------------------------------------------
__global__ __launch_bounds__(256) void attn_combine(
    const int* __restrict__ grp, const float* __restrict__ ml,
    const bf16* __restrict__ parts, bf16* __restrict__ O)
{
  const int meta = grp[4 * blockIdx.x];
  const int first = grp[4 * blockIdx.x + 1];
  const int n = grp[4 * blockIdx.x + 2];
  const int b = meta & 1, h = (meta >> 1) & 15, qt = (meta >> 5) & 15;
  const int t = threadIdx.x;
  const int row = t >> 1, cg = t & 1;

  float M = -1e30f;
  for (int c = 0; c < n; ++c) M = fmaxf(M, ml[(long long)(first + c) * 256 + row]);

  float acc[64];
#pragma unroll
  for (int j = 0; j < 64; ++j) acc[j] = 0.f;
  float den = 0.f;
  for (int c = 0; c < n; ++c) {
    const float* mlc = ml + (long long)(first + c) * 256;
    float w = __expf(mlc[row] - M);
    den = fmaf(w, mlc[128 + row], den);
    const bf16* p = parts + (long long)(first + c) * 16384 + row * 128 + cg * 64;
#pragma unroll
    for (int j8 = 0; j8 < 8; ++j8) {
      bf16x8 v = ((const bf16x8*)p)[j8];
#pragma unroll
      for (int k = 0; k < 8; ++k) acc[j8 * 8 + k] = fmaf(w, (float)v[k], acc[j8 * 8 + k]);
    }
  }
  float rd = 1.0f / den;
  long long qg = (long long)b * 2048 + qt * 128 + row;
  bf16* o = O + qg * 2048 + h * 128 + cg * 64;
#pragma unroll
  for (int j8 = 0; j8 < 8; ++j8) {
    bf16x8 v;
#pragma unroll
    for (int k = 0; k < 8; ++k) v[k] = (bf16)(acc[j8 * 8 + k] * rd);
    ((bf16x8*)o)[j8] = v;
  }
}

// ---------------------------------------------------------------------------
extern "C" void kernel_launch(void* const* d_in, const int* in_sizes, int n_in,
                              void* d_out, int out_size, void* d_ws, size_t ws_size,
                              hipStream_t stream) {
  (void)in_sizes; (void)n_in; (void)out_size; (void)ws_size;
  const float* hs  = (const float*)d_in[0];  // [2,2048,2048]
  const float* Wqd = (const float*)d_in[1];  // [1536,2048]
  const float* Wqu = (const float*)d_in[2];  // [2048,1536]
  const float* Wkv = (const float*)d_in[3];  // [512,2048]
  const float* kup = (const float*)d_in[4];  // [16,512,128]
  const float* vup = (const float*)d_in[5];  // [16,512,128]
  const float* Wo  = (const float*)d_in[6];  // [2048,2048]
  float* out = (float*)d_out;                // [2,2048,2048] fp32

  char* ws = (char*)d_ws;
  bf16* hsb  = (bf16*)ws; ws += (size_t)4096 * 2048 * 2;   // [also Ob]
  bf16* Wdcb = (bf16*)ws; ws += (size_t)2048 * 2048 * 2;   // concat(Wqd,Wkv)
  bf16* Wqub = (bf16*)ws; ws += (size_t)2048 * 1536 * 2;
  bf16* kupT = (bf16*)ws; ws += (size_t)16 * 128 * 512 * 2;
  bf16* vupT = (bf16*)ws; ws += (size_t)16 * 128 * 512 * 2;
  bf16* XC   = (bf16*)ws; ws += (size_t)4096 * 2048 * 2;   // [Xq | Cl] [also Wob]
  bf16* Qb   = (bf16*)ws; ws += (size_t)4096 * 2048 * 2;
  bf16* Kb   = (bf16*)ws; ws += (size_t)16 * 4096 * 128 * 2;
  bf16* VTb  = (bf16*)ws; ws += (size_t)16 * 128 * 4096 * 2;
  bf16* Cl   = XC + 1536;   // latent = cols [1536,2048) of XC, ld 2048
  bf16* Ob   = hsb;         // attn out aliases hsb
  bf16* Wob  = XC;          // Wo bf16 aliases XC

  // attention split-chunk scratch aliases Wdcb..vupT (dead by attention time):
  // [tbl 2048 int][grp 1024 int][ml 448*256 f32][parts 448*128*128 bf16] = 15.2 MB
  int*   tbl   = (int*)Wdcb;
  int*   grpd  = tbl + 2048;
  float* mld   = (float*)(grpd + 1024);
  bf16*  parts = (bf16*)(mld + 448 * 256);

  // fp32 -> bf16 converts
  cvt_f32_bf16<<<1024, 256, 0, stream>>>(hs, hsb, 4096 * 2048 / 4);
  cvt3_f32_bf16<<<1024, 256, 0, stream>>>(
      Wqd, Wdcb, 1536 * 2048 / 4,
      Wkv, Wdcb + (size_t)1536 * 2048, 512 * 2048 / 4,
      Wqu, Wqub, 2048 * 1536 / 4);
  transpose_cvt<<<dim3(2, 8, 16), 256, 0, stream>>>(kup, kupT, 512, 128);
  transpose_cvt<<<dim3(2, 8, 16), 256, 0, stream>>>(vup, vupT, 512, 128);

  // XC = hs * [Wq_down|Wkv_down]^T   [4096 x 2048 x 2048]
  gemm_nt<bf16><<<dim3(16, 32, 1), 256, 0, stream>>>(hsb, Wdcb, XC,
                                                     2048, 2048, 2048, 2048, 0, 0, 0);
  // Q = Xq * Wq_up^T                 [4096 x 2048 x 1536]
  gemm_nt<bf16><<<dim3(16, 32, 1), 256, 0, stream>>>(XC, Wqub, Qb,
                                                     2048, 1536, 2048, 1536, 0, 0, 0);
  // K[h] = C * k_upT[h]^T            [4096 x 128 x 512] x16
  gemm_nt<bf16><<<dim3(1, 32, 16), 256, 0, stream>>>(Cl, kupT, Kb,
                                                     2048, 512, 128, 512,
                                                     0, 128 * 512, (long long)4096 * 128);
  // VT[h] = v_upT[h] * C^T           [128 x 4096 x 512] x16
  gemm_nt<bf16><<<dim3(32, 1, 16), 256, 0, stream>>>(vupT, Cl, VTb,
                                                     512, 2048, 4096, 512,
                                                     128 * 512, 0, (long long)128 * 4096);
  // Wo convert (into XC region, now dead)
  cvt_f32_bf16<<<512, 256, 0, stream>>>(Wo, Wob, 2048 * 2048 / 4);
  // chunk table (Wdcb region dead now), then chunked attention + combine
  attn_setup<<<1, 64, 0, stream>>>(tbl, grpd);
  attn_kernel<<<dim3(ATTN_BLOCKS, 1, 1), 256, 0, stream>>>(Qb, Kb, VTb, Ob, tbl, mld, parts);
  attn_combine<<<dim3(COMB_BLOCKS, 1, 1), 256, 0, stream>>>(grpd, mld, parts, Ob);
  // out = O * Wo^T                   [4096 x 2048 x 2048], fp32 output
  gemm_nt<float><<<dim3(16, 32, 1), 256, 0, stream>>>(Ob, Wob, out,
                                                      2048, 2048, 2048, 2048, 0, 0, 0);
}

// Round 7
// 438.615 us; speedup vs baseline: 1.1760x; 1.1760x over previous
//
#include <hip/hip_runtime.h>
#include <math.h>

// MLA + ALiBi causal attention. fp32 in/out, bf16 MFMA internal compute.
// R7: (1) chunk tables computed at COMPILE TIME (R6's single-thread setup
// kernel cost ~80 us serial); (2) attn double-buffers K/V (80KB LDS) and
// drops to ONE barrier per tile (Psf is wave-private -> post-softmax barrier
// unnecessary), prefetch issued right after the barrier hides staging latency.

typedef __bf16 bf16;
typedef __bf16 bf16x8 __attribute__((ext_vector_type(8)));
typedef __bf16 bf16x4 __attribute__((ext_vector_type(4)));
typedef float f32x4 __attribute__((ext_vector_type(4)));

#define AS1 __attribute__((address_space(1)))
#define AS3 __attribute__((address_space(3)))

// Exact static decomposition (L=2048, 128-row q tiles, 64-key kv tiles,
// chunk = 8 kv tiles, ALiBi window WH[h]): per b: 172 direct + 224 chunks,
// 84 groups. Totals: 344 direct + 448 partial = 792 blocks; 168 groups.
#define ATTN_BLOCKS 792
#define COMB_BLOCKS 168

struct ATables {
  int tbl[ATTN_BLOCKS * 2];   // {meta, partIdx(-1=direct)}
  int grp[COMB_BLOCKS * 4];   // {meta, firstPart, nChunks, pad}
};

// meta = b | h<<1 | qt<<5 | cstart<<9 | clen<<16
constexpr ATables make_tables() {
  ATables T{};
  int WH[16] = {22,32,45,64,90,128,181,256,362,512,724,1024,1448,2048,2896,4096};
  int nc = 0, np = 0, ng = 0;
  for (int qt = 15; qt >= 0; --qt)
    for (int h = 15; h >= 0; --h)
      for (int b = 0; b < 2; ++b) {
        int q0 = qt * 128, nkv = 2 * qt + 2;
        int dlo = q0 - WH[h];
        int kv_lo = dlo > 0 ? (dlo >> 6) : 0;
        int span = nkv - kv_lo;
        int nch = (span + 7) >> 3;
        int base = b | (h << 1) | (qt << 5);
        if (nch == 1) {
          T.tbl[2 * nc] = base | (kv_lo << 9) | (span << 16);
          T.tbl[2 * nc + 1] = -1;
          ++nc;
        } else {
          T.grp[4 * ng] = base; T.grp[4 * ng + 1] = np; T.grp[4 * ng + 2] = nch;
          ++ng;
          for (int c = 0; c < nch; ++c) {
            int cs = kv_lo + c * 8;
            int cl = nkv - cs; if (cl > 8) cl = 8;
            T.tbl[2 * nc] = base | (cs << 9) | (cl << 16);
            T.tbl[2 * nc + 1] = np;
            ++nc; ++np;
          }
        }
      }
  return T;
}

__device__ const ATables g_tab = make_tables();

__device__ __forceinline__ void g2l16(const void* g, void* l) {
  // async global->LDS, 16B per lane; LDS dest is wave-uniform base + lane*16
  __builtin_amdgcn_global_load_lds((const AS1 void*)g, (AS3 void*)l, 16, 0, 0);
}

// ---------------------------------------------------------------------------
// fp32 -> bf16 elementwise convert (n4 = element count / 4)
// ---------------------------------------------------------------------------
__device__ __forceinline__ void cvt_seg(const float* __restrict__ in,
                                        bf16* __restrict__ out, int n4) {
  int i = blockIdx.x * 256 + threadIdx.x;
  const int stride = gridDim.x * 256;
  for (; i < n4; i += stride) {
    float4 v = ((const float4*)in)[i];
    bf16x4 o;
    o[0] = (bf16)v.x; o[1] = (bf16)v.y; o[2] = (bf16)v.z; o[3] = (bf16)v.w;
    ((bf16x4*)out)[i] = o;
  }
}

__global__ __launch_bounds__(256) void cvt_f32_bf16(
    const float* __restrict__ in, bf16* __restrict__ out, int n4) {
  cvt_seg(in, out, n4);
}

__global__ __launch_bounds__(256) void cvt3_f32_bf16(
    const float* __restrict__ s0, bf16* __restrict__ d0, int n0,
    const float* __restrict__ s1, bf16* __restrict__ d1, int n1,
    const float* __restrict__ s2, bf16* __restrict__ d2, int n2) {
  cvt_seg(s0, d0, n0);
  cvt_seg(s1, d1, n1);
  cvt_seg(s2, d2, n2);
}

// ---------------------------------------------------------------------------
// fused convert+transpose: fp32 [Z][R][D] -> bf16 [Z][D][R]. R%64==0, D%64==0.
// ---------------------------------------------------------------------------
__global__ __launch_bounds__(256) void transpose_cvt(
    const float* __restrict__ in, bf16* __restrict__ out, int R, int D)
{
  __shared__ bf16 tile[64][72];
  const long long base = (long long)blockIdx.z * R * D;
  const int r0 = blockIdx.y * 64, c0 = blockIdx.x * 64;
  const int t = threadIdx.x;
#pragma unroll
  for (int i = 0; i < 4; ++i) {
    int c = i * 256 + t;
    int rr = c >> 4, cc = (c & 15) << 2;
    float4 v = *(const float4*)&in[base + (long long)(r0 + rr) * D + c0 + cc];
    tile[rr][cc + 0] = (bf16)v.x;
    tile[rr][cc + 1] = (bf16)v.y;
    tile[rr][cc + 2] = (bf16)v.z;
    tile[rr][cc + 3] = (bf16)v.w;
  }
  __syncthreads();
#pragma unroll
  for (int i = 0; i < 2; ++i) {
    int c = i * 256 + t;
    int rr = c >> 3, cc = (c & 7) << 3;
    bf16x8 v;
#pragma unroll
    for (int j = 0; j < 8; ++j) v[j] = tile[cc + j][rr];
    *(bf16x8*)&out[base + (long long)(c0 + rr) * R + r0 + cc] = v;
  }
}

// ---------------------------------------------------------------------------
// NT GEMM: C[m,n] = sum_k A[m,k]*B[n,k]. 128x128 tile, BK=32, 4 waves.
// ---------------------------------------------------------------------------
template <typename CT>
__global__ __launch_bounds__(256) void gemm_nt(
    const bf16* __restrict__ A, const bf16* __restrict__ B, CT* __restrict__ C,
    int lda, int ldb, int ldc, int K, long long sA, long long sB, long long sC)
{
  A += (long long)blockIdx.z * sA;
  B += (long long)blockIdx.z * sB;
  C += (long long)blockIdx.z * sC;

  __shared__ bf16 As[128][32];
  __shared__ bf16 Bs[128][32];

  const int t = threadIdx.x;
  const int lane = t & 63, wave = t >> 6;
  const int wm = (wave >> 1) * 64, wn = (wave & 1) * 64;
  const int m0 = blockIdx.y * 128, n0 = blockIdx.x * 128;
  const int r16 = lane & 15, q8 = (lane >> 4) * 8;

  f32x4 acc[4][4] = {};

  for (int k0 = 0; k0 < K; k0 += 32) {
    __syncthreads();
#pragma unroll
    for (int r = 0; r < 2; ++r) {
      int c = r * 256 + t;
      int row = c >> 2, col = (c & 3) << 3;
      g2l16(A + (long long)(m0 + row) * lda + (k0 + col), &As[row][col]);
      g2l16(B + (long long)(n0 + row) * ldb + (k0 + col), &Bs[row][col]);
    }
    __syncthreads();

    bf16x8 af[4], bfr[4];
#pragma unroll
    for (int i = 0; i < 4; ++i) af[i]  = *(const bf16x8*)&As[wm + i * 16 + r16][q8];
#pragma unroll
    for (int i = 0; i < 4; ++i) bfr[i] = *(const bf16x8*)&Bs[wn + i * 16 + r16][q8];
#pragma unroll
    for (int mi = 0; mi < 4; ++mi)
#pragma unroll
      for (int ni = 0; ni < 4; ++ni)
        acc[mi][ni] = __builtin_amdgcn_mfma_f32_16x16x32_bf16(af[mi], bfr[ni], acc[mi][ni], 0, 0, 0);
  }

  const int quad = lane >> 4;
#pragma unroll
  for (int mi = 0; mi < 4; ++mi)
#pragma unroll
    for (int ni = 0; ni < 4; ++ni)
#pragma unroll
      for (int r = 0; r < 4; ++r) {
        int mm = m0 + wm + mi * 16 + quad * 4 + r;
        int nn = n0 + wn + ni * 16 + r16;
        C[(long long)mm * ldc + nn] = (CT)acc[mi][ni][r];
      }
}

// ---------------------------------------------------------------------------
// Flash attention, chunked + double-buffered. Block = table entry: 128 q rows
// of (b,h,qt) over KV tiles [cs, cs+cl). K/V double-buffered in LDS (80KB);
// ONE barrier per tile (Psf is wave-private: each wave writes/reads only its
// own 32 rows, so no post-softmax barrier). Prefetch of tile i+1 issued right
// after the barrier -> next barrier's vmcnt(0) drain finds it complete.
// Causal mask on any tile >= nkv-2. LDS XOR-swizzled (conflict-free).
// ---------------------------------------------------------------------------
__global__ __launch_bounds__(256) void attn_kernel(
    const bf16* __restrict__ Q, const bf16* __restrict__ Kh,
    const bf16* __restrict__ VT, bf16* __restrict__ O,
    float* __restrict__ ml, bf16* __restrict__ parts)
{
  const int L = 2048, HD = 128, D = 2048;
  const int meta = g_tab.tbl[2 * blockIdx.x];
  const int part = g_tab.tbl[2 * blockIdx.x + 1];
  const int b = meta & 1, h = (meta >> 1) & 15, qt = (meta >> 5) & 15;
  const int cs = (meta >> 9) & 127, cl = (meta >> 16) & 15;
  const int q0 = qt * 128, nkv = 2 * qt + 2;
  const int cend = cs + cl;
  // mask any diagonal tile (>= nkv-2) present in this chunk:
  const int mraw = nkv - 2 > cs ? nkv - 2 : cs;
  const int mstart = mraw < cend ? mraw : cend;

  const int t = threadIdx.x, wave = t >> 6, lane = t & 63;
  const int col = lane & 15, quad = lane >> 4;
  const float slope = exp2f(-0.5f * (float)(h + 1));
  const float slope16 = slope * 16.0f;
  const float scale = 0.08838834764831845f;   // 1/sqrt(128)

  __shared__ bf16 Ksf[2][64 * 128];   // [key][d],  16 chunks/row, swz mask 15
  __shared__ bf16 Vsf[2][128 * 64];   // [d][key],   8 chunks/row, swz mask 7
  __shared__ bf16 Psf[128 * 64];      // [q][key],  wave-private 32-row bands

  const long long qrow0 = (long long)(b * L + q0 + wave * 32);
  const long long kbase = (long long)(h * 4096 + b * L) * HD;
  const long long vbase = (long long)(h * HD) * 4096 + b * L;

  auto stage = [&](int buf, int itile) {
    const int kv0 = itile << 6;
#pragma unroll
    for (int i = 0; i < 4; ++i) {
      int P = i * 256 + t;   // physical 16B chunk index (contiguous per wave)
      {  // K: row = P>>4, phys chunk p = P&15, logical chunk = p ^ (row&15)
        int rr = P >> 4, cc = ((P & 15) ^ (rr & 15)) << 3;
        g2l16(Kh + kbase + (long long)(kv0 + rr) * HD + cc, &Ksf[buf][P * 8]);
      }
      {  // V: row = P>>3, phys chunk p = P&7, logical chunk = p ^ (row&7)
        int rr = P >> 3, cc = ((P & 7) ^ (rr & 7)) << 3;
        g2l16(VT + vbase + (long long)rr * 4096 + kv0 + cc, &Vsf[buf][P * 8]);
      }
    }
  };

  bf16x8 qf[2][4];
#pragma unroll
  for (int mi = 0; mi < 2; ++mi)
#pragma unroll
    for (int ks = 0; ks < 4; ++ks)
      qf[mi][ks] = *(const bf16x8*)&Q[(qrow0 + mi * 16 + col) * D + h * HD + ks * 32 + quad * 8];

  f32x4 o_acc[2][8] = {};
  float m_i[2][4], l_i[2][4];   // l lane-partial (this lane's 4 cols)
#pragma unroll
  for (int mi = 0; mi < 2; ++mi)
#pragma unroll
    for (int r = 0; r < 4; ++r) { m_i[mi][r] = -1e30f; l_i[mi][r] = 0.f; }

  stage(0, cs);

  for (int it = cs; it < cend; ++it) {
    const int cur = (it - cs) & 1;
    const int kv0 = it << 6;
    const bool masked = (it >= mstart);   // wave-uniform

    __syncthreads();                      // drains vmcnt: Ks/Vs[cur] ready
    if (it + 1 < cend) stage(cur ^ 1, it + 1);   // prefetch next tile

    // S = Q K^T  (per wave: 2 m-tiles x 4 n-tiles, 4 k-steps over d=128)
    f32x4 s_acc[2][4] = {};
#pragma unroll
    for (int ks = 0; ks < 4; ++ks) {
      bf16x8 kf[4];
#pragma unroll
      for (int ni = 0; ni < 4; ++ni)
        kf[ni] = *(const bf16x8*)&Ksf[cur][(ni * 16 + col) * 128 +
                                          (((ks * 4 + quad) ^ col) << 3)];
#pragma unroll
      for (int mi = 0; mi < 2; ++mi)
#pragma unroll
        for (int ni = 0; ni < 4; ++ni)
          s_acc[mi][ni] = __builtin_amdgcn_mfma_f32_16x16x32_bf16(
              qf[mi][ks], kf[ni], s_acc[mi][ni], 0, 0, 0);
    }

    // online softmax; S row = quad*4+r (+16*mi), col = ni*16 + (lane&15)
#pragma unroll
    for (int mi = 0; mi < 2; ++mi) {
#pragma unroll
      for (int r = 0; r < 4; ++r) {
        const int rowq = wave * 32 + mi * 16 + quad * 4 + r;
        const int qg = q0 + rowq;
        const float sb = slope * (float)(qg - kv0 - col);   // dist at ni=0
        float sv[4];
#pragma unroll
        for (int ni = 0; ni < 4; ++ni)
          sv[ni] = fmaf(s_acc[mi][ni][r], scale, (float)ni * slope16 - sb);
        if (masked) {
#pragma unroll
          for (int ni = 0; ni < 4; ++ni)
            if (kv0 + ni * 16 + col > qg) sv[ni] = -1e30f;
        }
        float rm = fmaxf(fmaxf(sv[0], sv[1]), fmaxf(sv[2], sv[3]));
#pragma unroll
        for (int off = 1; off < 16; off <<= 1)
          rm = fmaxf(rm, __shfl_xor(rm, off, 64));
        const float mold = m_i[mi][r];
        float mnew = fmaxf(mold, rm);
        if (masked) mnew = fmaxf(mnew, -1e20f);   // all-masked-row floor
        const float alpha = __expf(mold - mnew);
        float ps = 0.f;
#pragma unroll
        for (int ni = 0; ni < 4; ++ni) {
          float pv = __expf(sv[ni] - mnew);
          ps += pv;
          // P[rowq][k], k=ni*16+col: chunk c=k>>3 -> phys c^(rowq&7), elem k&7
          Psf[rowq * 64 + ((((ni * 2) + (col >> 3)) ^ (rowq & 7)) << 3) +
              (col & 7)] = (bf16)pv;
        }
        l_i[mi][r] = fmaf(alpha, l_i[mi][r], ps);
        m_i[mi][r] = mnew;
#pragma unroll
        for (int di = 0; di < 8; ++di) o_acc[mi][di][r] *= alpha;
      }
    }

    // O += P V (no barrier needed: Psf band is wave-private; Vs double-buffered)
#pragma unroll
    for (int kstep = 0; kstep < 2; ++kstep) {
      bf16x8 pf[2];
#pragma unroll
      for (int mi = 0; mi < 2; ++mi)
        pf[mi] = *(const bf16x8*)&Psf[(wave * 32 + mi * 16 + col) * 64 +
                                      (((kstep * 4 + quad) ^ (col & 7)) << 3)];
#pragma unroll
      for (int di = 0; di < 8; ++di) {
        bf16x8 vf = *(const bf16x8*)&Vsf[cur][(di * 16 + col) * 64 +
                                             (((kstep * 4 + quad) ^ (col & 7)) << 3)];
#pragma unroll
        for (int mi = 0; mi < 2; ++mi)
          o_acc[mi][di] = __builtin_amdgcn_mfma_f32_16x16x32_bf16(
              pf[mi], vf, o_acc[mi][di], 0, 0, 0);
      }
    }
  }

  if (part < 0) {
    // direct: normalize (reduce lane-partial l over the 16-lane row group)
#pragma unroll
    for (int mi = 0; mi < 2; ++mi)
#pragma unroll
      for (int r = 0; r < 4; ++r) {
        float lt = l_i[mi][r];
#pragma unroll
        for (int off = 1; off < 16; off <<= 1)
          lt += __shfl_xor(lt, off, 64);
        float rl = 1.0f / lt;
        long long qg = qrow0 + mi * 16 + quad * 4 + r;
#pragma unroll
        for (int di = 0; di < 8; ++di)
          O[qg * D + h * HD + di * 16 + col] = (bf16)(o_acc[mi][di][r] * rl);
      }
  } else {
    // partial: store unnormalized O~ (bf16) + m,l (fp32 per row)
    bf16* pb = parts + (long long)part * 16384;
    float* mlp = ml + (long long)part * 256;
#pragma unroll
    for (int mi = 0; mi < 2; ++mi)
#pragma unroll
      for (int r = 0; r < 4; ++r) {
        float lt = l_i[mi][r];
#pragma unroll
        for (int off = 1; off < 16; off <<= 1)
          lt += __shfl_xor(lt, off, 64);
        int rowq = wave * 32 + mi * 16 + quad * 4 + r;
        if (col == 0) { mlp[rowq] = m_i[mi][r]; mlp[128 + rowq] = lt; }
#pragma unroll
        for (int di = 0; di < 8; ++di)
          pb[rowq * 128 + di * 16 + col] = (bf16)o_acc[mi][di][r];
      }
  }
}

// ---------------------------------------------------------------------------
// Combine partial chunks: O = sum_c e^(m_c-M) O~_c / sum_c e^(m_c-M) l_c.
// One block per group; thread t: row = t>>1, cols (t&1)*64..+63.
// ---------------------------------------------------------------------------
__global__ __launch_bounds__(256) void attn_combine(
    const float* __restrict__ ml, const bf16* __restrict__ parts,
    bf16* __restrict__ O)
{
  const int meta = g_tab.grp[4 * blockIdx.x];
  const int first = g_tab.grp[4 * blockIdx.x + 1];
  const int n = g_tab.grp[4 * blockIdx.x + 2];
  const int b = meta & 1, h = (meta >> 1) & 15, qt = (meta >> 5) & 15;
  const int t = threadIdx.x;
  const int row = t >> 1, cg = t & 1;

  float M = -1e30f;
  for (int c = 0; c < n; ++c) M = fmaxf(M, ml[(long long)(first + c) * 256 + row]);

  float acc[64];
#pragma unroll
  for (int j = 0; j < 64; ++j) acc[j] = 0.f;
  float den = 0.f;
  for (int c = 0; c < n; ++c) {
    const float* mlc = ml + (long long)(first + c) * 256;
    float w = __expf(mlc[row] - M);
    den = fmaf(w, mlc[128 + row], den);
    const bf16* p = parts + (long long)(first + c) * 16384 + row * 128 + cg * 64;
#pragma unroll
    for (int j8 = 0; j8 < 8; ++j8) {
      bf16x8 v = ((const bf16x8*)p)[j8];
#pragma unroll
      for (int k = 0; k < 8; ++k) acc[j8 * 8 + k] = fmaf(w, (float)v[k], acc[j8 * 8 + k]);
    }
  }
  float rd = 1.0f / den;
  long long qg = (long long)b * 2048 + qt * 128 + row;
  bf16* o = O + qg * 2048 + h * 128 + cg * 64;
#pragma unroll
  for (int j8 = 0; j8 < 8; ++j8) {
    bf16x8 v;
#pragma unroll
    for (int k = 0; k < 8; ++k) v[k] = (bf16)(acc[j8 * 8 + k] * rd);
    ((bf16x8*)o)[j8] = v;
  }
}

// ---------------------------------------------------------------------------
extern "C" void kernel_launch(void* const* d_in, const int* in_sizes, int n_in,
                              void* d_out, int out_size, void* d_ws, size_t ws_size,
                              hipStream_t stream) {
  (void)in_sizes; (void)n_in; (void)out_size; (void)ws_size;
  const float* hs  = (const float*)d_in[0];  // [2,2048,2048]
  const float* Wqd = (const float*)d_in[1];  // [1536,2048]
  const float* Wqu = (const float*)d_in[2];  // [2048,1536]
  const float* Wkv = (const float*)d_in[3];  // [512,2048]
  const float* kup = (const float*)d_in[4];  // [16,512,128]
  const float* vup = (const float*)d_in[5];  // [16,512,128]
  const float* Wo  = (const float*)d_in[6];  // [2048,2048]
  float* out = (float*)d_out;                // [2,2048,2048] fp32

  char* ws = (char*)d_ws;
  bf16* hsb  = (bf16*)ws; ws += (size_t)4096 * 2048 * 2;   // [also Ob]
  bf16* Wdcb = (bf16*)ws; ws += (size_t)2048 * 2048 * 2;   // concat(Wqd,Wkv)
  bf16* Wqub = (bf16*)ws; ws += (size_t)2048 * 1536 * 2;
  bf16* kupT = (bf16*)ws; ws += (size_t)16 * 128 * 512 * 2;
  bf16* vupT = (bf16*)ws; ws += (size_t)16 * 128 * 512 * 2;
  bf16* XC   = (bf16*)ws; ws += (size_t)4096 * 2048 * 2;   // [Xq | Cl] [also Wob]
  bf16* Qb   = (bf16*)ws; ws += (size_t)4096 * 2048 * 2;
  bf16* Kb   = (bf16*)ws; ws += (size_t)16 * 4096 * 128 * 2;
  bf16* VTb  = (bf16*)ws; ws += (size_t)16 * 128 * 4096 * 2;
  bf16* Cl   = XC + 1536;   // latent = cols [1536,2048) of XC, ld 2048
  bf16* Ob   = hsb;         // attn out aliases hsb
  bf16* Wob  = XC;          // Wo bf16 aliases XC

  // attention split scratch aliases Wdcb.. (dead by attention time):
  // [ml 448*256 f32][parts 448*128*128 bf16] = 15.1 MB
  float* mld   = (float*)Wdcb;
  bf16*  parts = (bf16*)(mld + 448 * 256);

  // fp32 -> bf16 converts
  cvt_f32_bf16<<<1024, 256, 0, stream>>>(hs, hsb, 4096 * 2048 / 4);
  cvt3_f32_bf16<<<1024, 256, 0, stream>>>(
      Wqd, Wdcb, 1536 * 2048 / 4,
      Wkv, Wdcb + (size_t)1536 * 2048, 512 * 2048 / 4,
      Wqu, Wqub, 2048 * 1536 / 4);
  transpose_cvt<<<dim3(2, 8, 16), 256, 0, stream>>>(kup, kupT, 512, 128);
  transpose_cvt<<<dim3(2, 8, 16), 256, 0, stream>>>(vup, vupT, 512, 128);

  // XC = hs * [Wq_down|Wkv_down]^T   [4096 x 2048 x 2048]
  gemm_nt<bf16><<<dim3(16, 32, 1), 256, 0, stream>>>(hsb, Wdcb, XC,
                                                     2048, 2048, 2048, 2048, 0, 0, 0);
  // Q = Xq * Wq_up^T                 [4096 x 2048 x 1536]
  gemm_nt<bf16><<<dim3(16, 32, 1), 256, 0, stream>>>(XC, Wqub, Qb,
                                                     2048, 1536, 2048, 1536, 0, 0, 0);
  // K[h] = C * k_upT[h]^T            [4096 x 128 x 512] x16
  gemm_nt<bf16><<<dim3(1, 32, 16), 256, 0, stream>>>(Cl, kupT, Kb,
                                                     2048, 512, 128, 512,
                                                     0, 128 * 512, (long long)4096 * 128);
  // VT[h] = v_upT[h] * C^T           [128 x 4096 x 512] x16
  gemm_nt<bf16><<<dim3(32, 1, 16), 256, 0, stream>>>(vupT, Cl, VTb,
                                                     512, 2048, 4096, 512,
                                                     128 * 512, 0, (long long)128 * 4096);
  // Wo convert (into XC region, now dead)
  cvt_f32_bf16<<<512, 256, 0, stream>>>(Wo, Wob, 2048 * 2048 / 4);
  // chunked attention + combine (tables are compile-time constants)
  attn_kernel<<<dim3(ATTN_BLOCKS, 1, 1), 256, 0, stream>>>(Qb, Kb, VTb, Ob, mld, parts);
  attn_combine<<<dim3(COMB_BLOCKS, 1, 1), 256, 0, stream>>>(mld, parts, Ob);
  // out = O * Wo^T                   [4096 x 2048 x 2048], fp32 output
  gemm_nt<float><<<dim3(16, 32, 1), 256, 0, stream>>>(Ob, Wob, out,
                                                      2048, 2048, 2048, 2048, 0, 0, 0);
}